// Round 1
// baseline (23576.424 us; speedup 1.0000x reference)
//
#include <hip/hip_runtime.h>
#include <hip/hip_bf16.h>

#define BB 256
#define TT 256
#define FF 511
#define UU 512

typedef __bf16 bf16_t;
typedef __bf16 bf16x8 __attribute__((ext_vector_type(8)));
typedef __bf16 bf16x2 __attribute__((ext_vector_type(2)));
typedef float f32x4 __attribute__((ext_vector_type(4)));

// ---------------------------------------------------------------------------
// Weight prep: W_T[n][k] (bf16), n in [0,2048), k in [0,1024).
// k<512 -> Wx[k][n], else Wh[k-512][n].  32x32 LDS tile transpose.
// grid = 64 (n tiles) * 32 (k tiles) = 2048 blocks, 256 threads.
// ---------------------------------------------------------------------------
__global__ __launch_bounds__(256) void prep_weights(
    const float* __restrict__ Wx, const float* __restrict__ Wh,
    bf16_t* __restrict__ Wt) {
  __shared__ float tile[32][33];
  int bn = blockIdx.x & 63;   // 64 n-tiles
  int bk = blockIdx.x >> 6;   // 32 k-tiles
  int tx = threadIdx.x & 31;
  int ty = threadIdx.x >> 5;  // 0..7
#pragma unroll
  for (int r = 0; r < 4; ++r) {
    int k = bk * 32 + ty + r * 8;
    int n = bn * 32 + tx;
    float v = (k < UU) ? Wx[(long)k * 2048 + n] : Wh[(long)(k - UU) * 2048 + n];
    tile[ty + r * 8][tx] = v;
  }
  __syncthreads();
#pragma unroll
  for (int r = 0; r < 4; ++r) {
    int n = bn * 32 + ty + r * 8;
    int k = bk * 32 + tx;
    Wt[(long)n * 1024 + k] = (bf16_t)tile[tx][ty + r * 8];
  }
}

// ---------------------------------------------------------------------------
// init: zero h ping-pong buffers (bf16) and c (fp32). 131072 elems each.
// grid 512 x 256
// ---------------------------------------------------------------------------
__global__ __launch_bounds__(256) void init_state(
    bf16_t* __restrict__ hb0, bf16_t* __restrict__ hb1, float* __restrict__ c) {
  int idx = blockIdx.x * 256 + threadIdx.x;
  hb0[idx] = (bf16_t)0.f;
  hb1[idx] = (bf16_t)0.f;
  c[idx] = 0.f;
}

// ---------------------------------------------------------------------------
// dec_in0 = mean over t of x[b,t,u]; u==511 -> score[b]. Writes bf16 xin.
// grid 512 x 256
// ---------------------------------------------------------------------------
__global__ __launch_bounds__(256) void mean_kernel(
    const float* __restrict__ inputs, const float* __restrict__ score,
    bf16_t* __restrict__ xin) {
  int idx = blockIdx.x * 256 + threadIdx.x;  // 0..131071
  int b = idx >> 9;
  int u = idx & 511;
  float s;
  if (u < FF) {
    float acc = 0.f;
    long base = (long)b * TT * FF + u;
    for (int t = 0; t < TT; ++t) acc += inputs[base + (long)t * FF];
    s = acc * (1.0f / TT);
  } else {
    s = score[b];
  }
  xin[idx] = (bf16_t)s;
}

// ---------------------------------------------------------------------------
// Fused LSTM step: z = [x_t || h] @ [Wx;Wh] + b, pointwise, write h/c.
// MFMA 16x16x32 bf16. Block = 256 thr = 4 waves. Tile: M=32 rows, J=32 cols
// (x4 gates). wave w: rows base +16*(w&1), j base +16*(w>>1); 4 acc frags =
// the 4 gates at the same (row, j) -> fused LSTM epilogue per lane.
// grid = 8 (M tiles) * 16 (J tiles) = 128 blocks.
// ENC=true: A0 = fp32 inputs[b,t,:]+score (col 511). ENC=false: A0 = bf16 xin.
// A1 = bf16 h_in (k in [512,1024)).
// ---------------------------------------------------------------------------
template <bool ENC>
__global__ __launch_bounds__(256) void lstm_step(
    const float* __restrict__ xin_f32,  // ENC: inputs [B,T,F]
    const float* __restrict__ score,    // ENC: [B]
    const bf16_t* __restrict__ xin_bf,  // DEC: [B,U]
    int t,                              // ENC timestep (enc_out slot)
    const bf16_t* __restrict__ Wt,      // [2048][1024] bf16
    const float* __restrict__ bias,     // [2048] fp32
    const bf16_t* __restrict__ h_in,    // [B,U] bf16
    bf16_t* __restrict__ h_out,         // [B,U] bf16
    float* __restrict__ c,              // [B,U] fp32 (in place)
    bf16_t* __restrict__ enc_out)       // [B,T,U] bf16 or nullptr
{
  const int lane = threadIdx.x & 63;
  const int wave = threadIdx.x >> 6;
  const int quad = lane >> 4;
  const int l16 = lane & 15;
  const int mtile = blockIdx.x & 7;
  const int jtile = blockIdx.x >> 3;
  const int row0 = mtile * 32 + (wave & 1) * 16;  // wave's 16-row base
  const int j0 = jtile * 32 + (wave >> 1) * 16;   // wave's 16-col base (per gate)
  const int arow = row0 + l16;

  f32x4 zero = {0.f, 0.f, 0.f, 0.f};
  f32x4 acc[4];
#pragma unroll
  for (int g = 0; g < 4; ++g) acc[g] = zero;

#pragma unroll 4
  for (int ko = 0; ko < 32; ++ko) {
    const int kk = ko * 32 + quad * 8;  // this lane's 8-elem k start
    bf16x8 a;
    if (kk < UU) {
      if (ENC) {
        long base = ((long)arow * TT + t) * FF;
        if (kk + 8 <= FF) {
#pragma unroll
          for (int j = 0; j < 8; ++j) a[j] = (bf16_t)xin_f32[base + kk + j];
        } else {
#pragma unroll
          for (int j = 0; j < 8; ++j) {
            int u = kk + j;
            a[j] = (bf16_t)(u < FF ? xin_f32[base + u] : score[arow]);
          }
        }
      } else {
        a = *(const bf16x8*)(xin_bf + arow * UU + kk);
      }
    } else {
      a = *(const bf16x8*)(h_in + arow * UU + (kk - UU));
    }
#pragma unroll
    for (int g = 0; g < 4; ++g) {
      int n = g * UU + j0 + l16;
      bf16x8 b = *(const bf16x8*)(Wt + (long)n * 1024 + kk);
      acc[g] = __builtin_amdgcn_mfma_f32_16x16x32_bf16(a, b, acc[g], 0, 0, 0);
    }
  }

  // Epilogue: lane holds rows row0+quad*4+r (r=0..3), col j0+l16, all 4 gates.
  const int j = j0 + l16;
  const float bi = bias[j];
  const float bf_ = bias[UU + j];
  const float bg = bias[2 * UU + j];
  const float bo = bias[3 * UU + j];
#pragma unroll
  for (int r = 0; r < 4; ++r) {
    int b_idx = row0 + quad * 4 + r;
    float zi = acc[0][r] + bi;
    float zf = acc[1][r] + bf_;
    float zg = acc[2][r] + bg;
    float zo = acc[3][r] + bo;
    float ig = 1.f / (1.f + expf(-zi));
    float fg = 1.f / (1.f + expf(-zf));
    float gg = tanhf(zg);
    float og = 1.f / (1.f + expf(-zo));
    long ci = (long)b_idx * UU + j;
    float cn = fg * c[ci] + ig * gg;
    float hn = og * tanhf(cn);
    c[ci] = cn;
    h_out[ci] = (bf16_t)hn;
    if (enc_out) enc_out[((long)b_idx * TT + t) * UU + j] = (bf16_t)hn;
  }
}

// ---------------------------------------------------------------------------
// Attention step: scores[t] = h[b]·enc_out[b,t,:]; p = softmax(s*pw+pb);
// out[b,s,:] = p; xin[b,:] = sum_t p[t]*enc_out[b,t,:].
// grid = 256 (one WG per batch row), 256 threads = 4 waves.
// ---------------------------------------------------------------------------
__global__ __launch_bounds__(256) void attention(
    const bf16_t* __restrict__ h,        // [B,U] (this step's new h)
    const bf16_t* __restrict__ enc_out,  // [B,T,U]
    const float* __restrict__ ptr_w, const float* __restrict__ ptr_b,
    float* __restrict__ out,             // [B,T,T]
    int s,                               // decoder step
    bf16_t* __restrict__ xin)            // [B,U] bf16 (next dec input)
{
  const int b = blockIdx.x;
  const int tid = threadIdx.x;
  const int wave = tid >> 6;
  const int lane = tid & 63;
  __shared__ float sc[TT];
  __shared__ float red[8];

  // h fragment: lane covers u = lane*8 .. lane*8+7
  bf16x8 hv = *(const bf16x8*)(h + b * UU + lane * 8);
  float hf[8];
#pragma unroll
  for (int j = 0; j < 8; ++j) hf[j] = (float)hv[j];

  const bf16_t* eb = enc_out + (long)b * TT * UU;

  // Pass 1: scores (each wave owns 64 contiguous t, 2-way ILP)
  for (int t0 = wave * 64; t0 < wave * 64 + 64; t0 += 2) {
    bf16x8 e0 = *(const bf16x8*)(eb + (long)t0 * UU + lane * 8);
    bf16x8 e1 = *(const bf16x8*)(eb + (long)(t0 + 1) * UU + lane * 8);
    float d0 = 0.f, d1 = 0.f;
#pragma unroll
    for (int j = 0; j < 8; ++j) {
      d0 += hf[j] * (float)e0[j];
      d1 += hf[j] * (float)e1[j];
    }
#pragma unroll
    for (int m = 32; m; m >>= 1) {
      d0 += __shfl_xor(d0, m, 64);
      d1 += __shfl_xor(d1, m, 64);
    }
    if (lane == 0) {
      sc[t0] = d0;
      sc[t0 + 1] = d1;
    }
  }
  __syncthreads();

  // Softmax over 256 scores (one per thread)
  const float pw = *ptr_w, pb = *ptr_b;
  float v = sc[tid] * pw + pb;
  float mx = v;
#pragma unroll
  for (int m = 32; m; m >>= 1) mx = fmaxf(mx, __shfl_xor(mx, m, 64));
  if (lane == 0) red[wave] = mx;
  __syncthreads();
  mx = fmaxf(fmaxf(red[0], red[1]), fmaxf(red[2], red[3]));
  float e = expf(v - mx);
  float sm = e;
#pragma unroll
  for (int m = 32; m; m >>= 1) sm += __shfl_xor(sm, m, 64);
  if (lane == 0) red[4 + wave] = sm;
  __syncthreads();
  float denom = red[4] + red[5] + red[6] + red[7];
  float p = e / denom;
  out[((long)b * TT + s) * TT + tid] = p;
  sc[tid] = p;  // reuse LDS as softmax weights
  __syncthreads();

  // Pass 2: context. thread owns u = 2*tid, 2*tid+1.
  float a0 = 0.f, a1 = 0.f;
#pragma unroll 4
  for (int t = 0; t < TT; ++t) {
    float w = sc[t];
    bf16x2 ev = *(const bf16x2*)(eb + (long)t * UU + 2 * tid);
    a0 += w * (float)ev[0];
    a1 += w * (float)ev[1];
  }
  bf16x2 o;
  o[0] = (bf16_t)a0;
  o[1] = (bf16_t)a1;
  *(bf16x2*)(xin + b * UU + 2 * tid) = o;
}

// ---------------------------------------------------------------------------
extern "C" void kernel_launch(void* const* d_in, const int* in_sizes, int n_in,
                              void* d_out, int out_size, void* d_ws,
                              size_t ws_size, hipStream_t stream) {
  const float* inputs = (const float*)d_in[0];
  const float* score = (const float*)d_in[1];
  const float* enc_Wx = (const float*)d_in[2];
  const float* enc_Wh = (const float*)d_in[3];
  const float* enc_b = (const float*)d_in[4];
  const float* dec_Wx = (const float*)d_in[5];
  const float* dec_Wh = (const float*)d_in[6];
  const float* dec_b = (const float*)d_in[7];
  const float* ptr_w = (const float*)d_in[8];
  const float* ptr_b = (const float*)d_in[9];
  float* out = (float*)d_out;

  char* ws = (char*)d_ws;
  size_t off = 0;
  bf16_t* WencT = (bf16_t*)(ws + off); off += (size_t)2048 * 1024 * 2;       // 4 MiB
  bf16_t* WdecT = (bf16_t*)(ws + off); off += (size_t)2048 * 1024 * 2;       // 4 MiB
  bf16_t* enc_out = (bf16_t*)(ws + off); off += (size_t)BB * TT * UU * 2;    // 64 MiB
  bf16_t* hb0 = (bf16_t*)(ws + off); off += (size_t)BB * UU * 2;             // 256 KiB
  bf16_t* hb1 = (bf16_t*)(ws + off); off += (size_t)BB * UU * 2;             // 256 KiB
  float* cbuf = (float*)(ws + off); off += (size_t)BB * UU * 4;              // 512 KiB
  bf16_t* xin = (bf16_t*)(ws + off); off += (size_t)BB * UU * 2;             // 256 KiB
  if (ws_size < off) return;  // not enough scratch; fail cleanly

  prep_weights<<<2048, 256, 0, stream>>>(enc_Wx, enc_Wh, WencT);
  prep_weights<<<2048, 256, 0, stream>>>(dec_Wx, dec_Wh, WdecT);
  init_state<<<512, 256, 0, stream>>>(hb0, hb1, cbuf);
  mean_kernel<<<512, 256, 0, stream>>>(inputs, score, xin);

  bf16_t* hp[2] = {hb0, hb1};
  int p = 0;
  // Encoder: 256 fused LSTM steps
  for (int t = 0; t < TT; ++t) {
    lstm_step<true><<<128, 256, 0, stream>>>(inputs, score, nullptr, t, WencT,
                                             enc_b, hp[p], hp[1 - p], cbuf,
                                             enc_out);
    p ^= 1;
  }
  // Decoder: 256 steps of (LSTM, attention)
  for (int s = 0; s < TT; ++s) {
    lstm_step<false><<<128, 256, 0, stream>>>(nullptr, nullptr, xin, 0, WdecT,
                                              dec_b, hp[p], hp[1 - p], cbuf,
                                              nullptr);
    attention<<<256, 256, 0, stream>>>(hp[1 - p], enc_out, ptr_w, ptr_b, out,
                                       s, xin);
    p ^= 1;
  }
}

// Round 2
// 12064.291 us; speedup vs baseline: 1.9542x; 1.9542x over previous
//
#include <hip/hip_runtime.h>
#include <hip/hip_bf16.h>

#define BB 256
#define TT 256
#define FF 511
#define UU 512

typedef __bf16 bf16_t;
typedef __bf16 bf16x8 __attribute__((ext_vector_type(8)));
typedef __bf16 bf16x2 __attribute__((ext_vector_type(2)));
typedef float f32x4 __attribute__((ext_vector_type(4)));

// ---------------------------------------------------------------------------
// Weight prep: W_T[n][k] (bf16), n in [0,2048), k in [0,1024).
// k<512 -> Wx[k][n], else Wh[k-512][n].  32x32 LDS tile transpose.
// grid = 64 (n tiles) * 32 (k tiles) = 2048 blocks, 256 threads.
// ---------------------------------------------------------------------------
__global__ __launch_bounds__(256) void prep_weights(
    const float* __restrict__ Wx, const float* __restrict__ Wh,
    bf16_t* __restrict__ Wt) {
  __shared__ float tile[32][33];
  int bn = blockIdx.x & 63;   // 64 n-tiles
  int bk = blockIdx.x >> 6;   // 32 k-tiles
  int tx = threadIdx.x & 31;
  int ty = threadIdx.x >> 5;  // 0..7
#pragma unroll
  for (int r = 0; r < 4; ++r) {
    int k = bk * 32 + ty + r * 8;
    int n = bn * 32 + tx;
    float v = (k < UU) ? Wx[(long)k * 2048 + n] : Wh[(long)(k - UU) * 2048 + n];
    tile[ty + r * 8][tx] = v;
  }
  __syncthreads();
#pragma unroll
  for (int r = 0; r < 4; ++r) {
    int n = bn * 32 + ty + r * 8;
    int k = bk * 32 + tx;
    Wt[(long)n * 1024 + k] = (bf16_t)tile[tx][ty + r * 8];
  }
}

// ---------------------------------------------------------------------------
// prep_x: Xbf[t][b][u] = bf16(inputs[b][t][u]) for u<511, score[b] at u=511.
// Each thread handles 2 consecutive u. grid = 65536 x 256.
// ---------------------------------------------------------------------------
__global__ __launch_bounds__(256) void prep_x(
    const float* __restrict__ inputs, const float* __restrict__ score,
    bf16_t* __restrict__ X) {
  int gid = blockIdx.x * 256 + threadIdx.x;  // 16.7M
  int u = (gid & 255) * 2;
  int b = (gid >> 8) & 255;
  int t = gid >> 16;
  long ibase = (long)b * TT * FF + (long)t * FF;
  float v0 = inputs[ibase + u];
  float v1 = (u + 1 < FF) ? inputs[ibase + u + 1] : score[b];
  bf16x2 o;
  o[0] = (bf16_t)v0;
  o[1] = (bf16_t)v1;
  *(bf16x2*)(X + (long)t * BB * UU + b * UU + u) = o;
}

// ---------------------------------------------------------------------------
// init: zero h ping-pong buffers (bf16) and c (fp32). 131072 elems each.
// ---------------------------------------------------------------------------
__global__ __launch_bounds__(256) void init_state(
    bf16_t* __restrict__ hb0, bf16_t* __restrict__ hb1, float* __restrict__ c) {
  int idx = blockIdx.x * 256 + threadIdx.x;
  hb0[idx] = (bf16_t)0.f;
  hb1[idx] = (bf16_t)0.f;
  c[idx] = 0.f;
}

// ---------------------------------------------------------------------------
// dec_in0 = mean over t of X[t][b][u] (score col averages to itself).
// grid 512 x 256. Coalesced: consecutive threads -> consecutive u.
// ---------------------------------------------------------------------------
__global__ __launch_bounds__(256) void mean_kernel(
    const bf16_t* __restrict__ X, bf16_t* __restrict__ xin) {
  int idx = blockIdx.x * 256 + threadIdx.x;  // b*512+u
  float acc = 0.f;
  for (int t = 0; t < TT; ++t) acc += (float)X[(long)t * BB * UU + idx];
  xin[idx] = (bf16_t)(acc * (1.0f / TT));
}

// ---------------------------------------------------------------------------
// Fused LSTM step. 1 wave per block, grid = 16 mtiles x 32 jtiles = 512.
// Wave: 16 rows x 16 j-cols x 4 gates (acc[4]), K=1024 (x||h stacked).
// xin: bf16 [B,U] slice (enc: Xbf + t*B*U; dec: attention output).
// ---------------------------------------------------------------------------
__global__ __launch_bounds__(64) void lstm_step(
    const bf16_t* __restrict__ xin,     // [B,U] bf16
    const bf16_t* __restrict__ Wt,      // [2048][1024] bf16
    const float* __restrict__ bias,     // [2048] fp32
    const bf16_t* __restrict__ h_in,    // [B,U] bf16
    bf16_t* __restrict__ h_out,         // [B,U] bf16
    float* __restrict__ c,              // [B,U] fp32 (in place)
    bf16_t* __restrict__ enc_out,       // [B,T,U] bf16 or nullptr
    int t)                              // enc_out slot
{
  const int lane = threadIdx.x;
  const int quad = lane >> 4;
  const int l16 = lane & 15;
  const int mtile = blockIdx.x & 15;
  const int jtile = blockIdx.x >> 4;
  const int row0 = mtile * 16;
  const int j0 = jtile * 16;
  const int arow = row0 + l16;

  f32x4 zero = {0.f, 0.f, 0.f, 0.f};
  f32x4 acc[4];
#pragma unroll
  for (int g = 0; g < 4; ++g) acc[g] = zero;

#pragma unroll 4
  for (int ko = 0; ko < 32; ++ko) {
    const int kk = ko * 32 + quad * 8;  // this lane's 8-elem k start
    bf16x8 a;
    if (kk < UU) {
      a = *(const bf16x8*)(xin + arow * UU + kk);
    } else {
      a = *(const bf16x8*)(h_in + arow * UU + (kk - UU));
    }
#pragma unroll
    for (int g = 0; g < 4; ++g) {
      int n = g * UU + j0 + l16;
      bf16x8 b = *(const bf16x8*)(Wt + (long)n * 1024 + kk);
      acc[g] = __builtin_amdgcn_mfma_f32_16x16x32_bf16(a, b, acc[g], 0, 0, 0);
    }
  }

  // Epilogue: lane holds rows row0+quad*4+r (r=0..3), col j0+l16, all 4 gates.
  const int j = j0 + l16;
  const float bi = bias[j];
  const float bf_ = bias[UU + j];
  const float bg = bias[2 * UU + j];
  const float bo = bias[3 * UU + j];
#pragma unroll
  for (int r = 0; r < 4; ++r) {
    int b_idx = row0 + quad * 4 + r;
    float zi = acc[0][r] + bi;
    float zf = acc[1][r] + bf_;
    float zg = acc[2][r] + bg;
    float zo = acc[3][r] + bo;
    float ig = 1.f / (1.f + __expf(-zi));
    float fg = 1.f / (1.f + __expf(-zf));
    float gg = tanhf(zg);
    float og = 1.f / (1.f + __expf(-zo));
    long ci = (long)b_idx * UU + j;
    float cn = fg * c[ci] + ig * gg;
    float hn = og * tanhf(cn);
    c[ci] = cn;
    h_out[ci] = (bf16_t)hn;
    if (enc_out) enc_out[((long)b_idx * TT + t) * UU + j] = (bf16_t)hn;
  }
}

// ---------------------------------------------------------------------------
// Attention step, single-pass online softmax (flash-style, 8-t chunks).
// grid = 256 (one WG per batch row), 256 threads = 4 waves.
// Wave w owns t in [w*64, w*64+64); lane owns u-slice lane*8..lane*8+7.
// Raw scores kept in LDS; p[t] recomputed from global (M, L) at the end.
// ---------------------------------------------------------------------------
__global__ __launch_bounds__(256) void attention(
    const bf16_t* __restrict__ h,        // [B,U] (this step's new h)
    const bf16_t* __restrict__ enc_out,  // [B,T,U]
    const float* __restrict__ ptr_w, const float* __restrict__ ptr_b,
    float* __restrict__ out,             // [B,T,T]
    int s,                               // decoder step
    bf16_t* __restrict__ xin)            // [B,U] bf16 (next dec input)
{
  const int b = blockIdx.x;
  const int tid = threadIdx.x;
  const int wave = tid >> 6;
  const int lane = tid & 63;
  __shared__ float sc[TT];        // raw scaled scores v[t]
  __shared__ float ctxs[4][UU];   // per-wave context partials
  __shared__ float mL[4], lL[4];

  bf16x8 hv = *(const bf16x8*)(h + b * UU + lane * 8);
  float hf[8];
#pragma unroll
  for (int j = 0; j < 8; ++j) hf[j] = (float)hv[j];

  const bf16_t* eb = enc_out + (long)b * TT * UU;
  const float pw = *ptr_w, pb = *ptr_b;

  float m = -1e30f, l = 0.f;
  float ctx[8];
#pragma unroll
  for (int j = 0; j < 8; ++j) ctx[j] = 0.f;

  for (int ch = 0; ch < 8; ++ch) {
    const int tb = wave * 64 + ch * 8;
    bf16x8 er[8];
#pragma unroll
    for (int q = 0; q < 8; ++q)
      er[q] = *(const bf16x8*)(eb + (long)(tb + q) * UU + lane * 8);
    float v[8];
#pragma unroll
    for (int q = 0; q < 8; ++q) {
      float d = 0.f;
#pragma unroll
      for (int j = 0; j < 8; ++j) d += hf[j] * (float)er[q][j];
#pragma unroll
      for (int mm = 32; mm; mm >>= 1) d += __shfl_xor(d, mm, 64);
      v[q] = d * pw + pb;
    }
    if (lane == 0) {
#pragma unroll
      for (int q = 0; q < 8; ++q) sc[tb + q] = v[q];
    }
    float mx = v[0];
#pragma unroll
    for (int q = 1; q < 8; ++q) mx = fmaxf(mx, v[q]);
    float mn = fmaxf(m, mx);
    float scale = __expf(m - mn);  // first chunk: exp(-inf)=0 zeroes l/ctx
    l *= scale;
#pragma unroll
    for (int j = 0; j < 8; ++j) ctx[j] *= scale;
#pragma unroll
    for (int q = 0; q < 8; ++q) {
      float w = __expf(v[q] - mn);
      l += w;
#pragma unroll
      for (int j = 0; j < 8; ++j) ctx[j] += w * (float)er[q][j];
    }
    m = mn;
  }

  // Publish per-wave state
#pragma unroll
  for (int j = 0; j < 8; ++j) ctxs[wave][lane * 8 + j] = ctx[j];
  if (lane == 0) {
    mL[wave] = m;
    lL[wave] = l;
  }
  __syncthreads();

  const float M = fmaxf(fmaxf(mL[0], mL[1]), fmaxf(mL[2], mL[3]));
  const float s0 = __expf(mL[0] - M), s1 = __expf(mL[1] - M),
              s2 = __expf(mL[2] - M), s3 = __expf(mL[3] - M);
  const float L = lL[0] * s0 + lL[1] * s1 + lL[2] * s2 + lL[3] * s3;
  const float rinvL = 1.f / L;

  out[((long)b * TT + s) * TT + tid] = __expf(sc[tid] - M) * rinvL;

  const int u0 = 2 * tid;
  float a0 = ctxs[0][u0] * s0 + ctxs[1][u0] * s1 + ctxs[2][u0] * s2 +
             ctxs[3][u0] * s3;
  float a1 = ctxs[0][u0 + 1] * s0 + ctxs[1][u0 + 1] * s1 +
             ctxs[2][u0 + 1] * s2 + ctxs[3][u0 + 1] * s3;
  bf16x2 o;
  o[0] = (bf16_t)(a0 * rinvL);
  o[1] = (bf16_t)(a1 * rinvL);
  *(bf16x2*)(xin + b * UU + u0) = o;
}

// ---------------------------------------------------------------------------
extern "C" void kernel_launch(void* const* d_in, const int* in_sizes, int n_in,
                              void* d_out, int out_size, void* d_ws,
                              size_t ws_size, hipStream_t stream) {
  const float* inputs = (const float*)d_in[0];
  const float* score = (const float*)d_in[1];
  const float* enc_Wx = (const float*)d_in[2];
  const float* enc_Wh = (const float*)d_in[3];
  const float* enc_b = (const float*)d_in[4];
  const float* dec_Wx = (const float*)d_in[5];
  const float* dec_Wh = (const float*)d_in[6];
  const float* dec_b = (const float*)d_in[7];
  const float* ptr_w = (const float*)d_in[8];
  const float* ptr_b = (const float*)d_in[9];
  float* out = (float*)d_out;

  char* ws = (char*)d_ws;
  size_t off = 0;
  bf16_t* WencT = (bf16_t*)(ws + off); off += (size_t)2048 * 1024 * 2;       // 4 MiB
  bf16_t* WdecT = (bf16_t*)(ws + off); off += (size_t)2048 * 1024 * 2;       // 4 MiB
  bf16_t* enc_out = (bf16_t*)(ws + off); off += (size_t)BB * TT * UU * 2;    // 64 MiB
  bf16_t* Xbf = (bf16_t*)(ws + off); off += (size_t)TT * BB * UU * 2;        // 64 MiB
  bf16_t* hb0 = (bf16_t*)(ws + off); off += (size_t)BB * UU * 2;             // 256 KiB
  bf16_t* hb1 = (bf16_t*)(ws + off); off += (size_t)BB * UU * 2;             // 256 KiB
  float* cbuf = (float*)(ws + off); off += (size_t)BB * UU * 4;              // 512 KiB
  bf16_t* xin = (bf16_t*)(ws + off); off += (size_t)BB * UU * 2;             // 256 KiB
  if (ws_size < off) return;  // insufficient scratch -> loud absmax failure

  prep_weights<<<2048, 256, 0, stream>>>(enc_Wx, enc_Wh, WencT);
  prep_weights<<<2048, 256, 0, stream>>>(dec_Wx, dec_Wh, WdecT);
  prep_x<<<65536, 256, 0, stream>>>(inputs, score, Xbf);
  init_state<<<512, 256, 0, stream>>>(hb0, hb1, cbuf);
  mean_kernel<<<512, 256, 0, stream>>>(Xbf, xin);

  bf16_t* hp[2] = {hb0, hb1};
  int p = 0;
  // Encoder: 256 fused LSTM steps
  for (int t = 0; t < TT; ++t) {
    lstm_step<<<512, 64, 0, stream>>>(Xbf + (long)t * BB * UU, WencT, enc_b,
                                      hp[p], hp[1 - p], cbuf, enc_out, t);
    p ^= 1;
  }
  // Decoder: 256 steps of (LSTM, attention)
  for (int s = 0; s < TT; ++s) {
    lstm_step<<<512, 64, 0, stream>>>(xin, WdecT, dec_b, hp[p], hp[1 - p],
                                      cbuf, nullptr, 0);
    attention<<<256, 256, 0, stream>>>(hp[1 - p], enc_out, ptr_w, ptr_b, out,
                                       s, xin);
    p ^= 1;
  }
}

// Round 3
// 11417.824 us; speedup vs baseline: 2.0649x; 1.0566x over previous
//
#include <hip/hip_runtime.h>
#include <hip/hip_bf16.h>

#define BB 256
#define TT 256
#define FF 511
#define UU 512

typedef __bf16 bf16_t;
typedef __bf16 bf16x8 __attribute__((ext_vector_type(8)));
typedef __bf16 bf16x2 __attribute__((ext_vector_type(2)));
typedef float f32x4 __attribute__((ext_vector_type(4)));

__device__ __forceinline__ float fast_sigmoid(float x) {
  return 1.f / (1.f + __expf(-x));
}
__device__ __forceinline__ float fast_tanh(float x) {
  float a = fabsf(x);
  float t = 1.f - 2.f / (__expf(2.f * a) + 1.f);  // exp(inf)->inf -> t=1, safe
  return copysignf(t, x);
}

// ---------------------------------------------------------------------------
// Weight prep -> fragment-major packed layout:
// P[ntile][ko][lane][8] bf16, ntile=n/16 (n in [0,2048)), ko=k/32 (k in [0,1024)).
// lane -> (l16 = n offset, quad -> k offset quad*8). k<512 from Wx, else Wh.
// grid = 128 ntiles * 32 ko = 4096 blocks x 64 threads. One-time cost.
// ---------------------------------------------------------------------------
__global__ __launch_bounds__(64) void prep_weights(
    const float* __restrict__ Wx, const float* __restrict__ Wh,
    bf16_t* __restrict__ Wp) {
  int bid = blockIdx.x;  // ntile*32 + ko
  int ko = bid & 31;
  int ntile = bid >> 5;
  int lane = threadIdx.x;
  int n = ntile * 16 + (lane & 15);
  int kb = ko * 32 + (lane >> 4) * 8;  // 8-aligned; never straddles 512
  const float* src = (kb < UU) ? Wx : Wh;
  int krel = (kb < UU) ? kb : kb - UU;
  bf16x8 v;
#pragma unroll
  for (int j = 0; j < 8; ++j) v[j] = (bf16_t)src[(long)(krel + j) * 2048 + n];
  *(bf16x8*)(Wp + (long)bid * 512 + lane * 8) = v;
}

// ---------------------------------------------------------------------------
// prep_x: Xbf[t][b][u] = bf16(inputs[b][t][u]) for u<511, score[b] at u=511.
// ---------------------------------------------------------------------------
__global__ __launch_bounds__(256) void prep_x(
    const float* __restrict__ inputs, const float* __restrict__ score,
    bf16_t* __restrict__ X) {
  int gid = blockIdx.x * 256 + threadIdx.x;
  int u = (gid & 255) * 2;
  int b = (gid >> 8) & 255;
  int t = gid >> 16;
  long ibase = (long)b * TT * FF + (long)t * FF;
  float v0 = inputs[ibase + u];
  float v1 = (u + 1 < FF) ? inputs[ibase + u + 1] : score[b];
  bf16x2 o;
  o[0] = (bf16_t)v0;
  o[1] = (bf16_t)v1;
  *(bf16x2*)(X + (long)t * BB * UU + b * UU + u) = o;
}

__global__ __launch_bounds__(256) void init_state(
    bf16_t* __restrict__ hb0, bf16_t* __restrict__ hb1, float* __restrict__ c) {
  int idx = blockIdx.x * 256 + threadIdx.x;
  hb0[idx] = (bf16_t)0.f;
  hb1[idx] = (bf16_t)0.f;
  c[idx] = 0.f;
}

__global__ __launch_bounds__(256) void mean_kernel(
    const bf16_t* __restrict__ X, bf16_t* __restrict__ xin) {
  int idx = blockIdx.x * 256 + threadIdx.x;  // b*512+u
  float acc = 0.f;
  for (int t = 0; t < TT; ++t) acc += (float)X[(long)t * BB * UU + idx];
  xin[idx] = (bf16_t)(acc * (1.0f / TT));
}

// ---------------------------------------------------------------------------
// Fused LSTM step, K-split across 4 waves. Block = 256 thr = 4 waves.
// Tile: 16 rows (mtile) x 16 j-cols (jt16) x 4 gates; K=1024 split 256/wave.
// Wave w: ko in [w*8, w*8+8); partial f32x4 acc[4]; waves 1-3 spill to LDS;
// wave 0 reduces + fused LSTM epilogue. grid = 16 x 32 = 512 blocks.
// B-operand from packed P: one 16B/lane coalesced load per (g, ko).
// ---------------------------------------------------------------------------
__global__ __launch_bounds__(256, 2) void lstm_step(
    const bf16_t* __restrict__ xin,     // [B,U] bf16
    const bf16_t* __restrict__ Wp,      // packed fragments
    const float* __restrict__ bias,     // [2048]
    const bf16_t* __restrict__ h_in,    // [B,U] bf16
    bf16_t* __restrict__ h_out,         // [B,U] bf16
    float* __restrict__ c,              // [B,U] fp32 (in place)
    bf16_t* __restrict__ enc_out,       // [B,T,U] or nullptr
    int t) {
  const int tid = threadIdx.x;
  const int wave = tid >> 6;
  const int lane = tid & 63;
  const int quad = lane >> 4;
  const int l16 = lane & 15;
  const int mtile = blockIdx.x & 15;
  const int jt16 = blockIdx.x >> 4;  // 0..31
  const int row0 = mtile * 16;
  const int arow = row0 + l16;

  __shared__ float red[3][4][64][4];  // [src wave-1][gate][lane][4]

  f32x4 acc[4];
#pragma unroll
  for (int g = 0; g < 4; ++g) acc[g] = (f32x4){0.f, 0.f, 0.f, 0.f};

  const bf16_t* abase = (wave < 2) ? xin : h_in;
  const int kh = (wave & 1) * 256;  // k offset within 512-half

#pragma unroll
  for (int ko_l = 0; ko_l < 8; ++ko_l) {
    const int kk = kh + ko_l * 32 + quad * 8;
    bf16x8 a = *(const bf16x8*)(abase + arow * UU + kk);
    const int ko = wave * 8 + ko_l;  // global 0..31
#pragma unroll
    for (int g = 0; g < 4; ++g) {
      const long fidx = ((long)(g * 32 + jt16) * 32 + ko) * 512 + lane * 8;
      bf16x8 b = *(const bf16x8*)(Wp + fidx);
      acc[g] = __builtin_amdgcn_mfma_f32_16x16x32_bf16(a, b, acc[g], 0, 0, 0);
    }
  }

  if (wave != 0) {
#pragma unroll
    for (int g = 0; g < 4; ++g) *(f32x4*)&red[wave - 1][g][lane][0] = acc[g];
  }
  __syncthreads();
  if (wave != 0) return;

#pragma unroll
  for (int s = 0; s < 3; ++s)
#pragma unroll
    for (int g = 0; g < 4; ++g) acc[g] += *(const f32x4*)&red[s][g][lane][0];

  // Epilogue: lane holds rows row0+quad*4+r, col jt16*16+l16, all 4 gates.
  const int j = jt16 * 16 + l16;
  const float bi = bias[j];
  const float bf_ = bias[UU + j];
  const float bg = bias[2 * UU + j];
  const float bo = bias[3 * UU + j];
#pragma unroll
  for (int r = 0; r < 4; ++r) {
    int b_idx = row0 + quad * 4 + r;
    float ig = fast_sigmoid(acc[0][r] + bi);
    float fg = fast_sigmoid(acc[1][r] + bf_);
    float gg = fast_tanh(acc[2][r] + bg);
    float og = fast_sigmoid(acc[3][r] + bo);
    long ci = (long)b_idx * UU + j;
    float cn = fg * c[ci] + ig * gg;
    float hn = og * fast_tanh(cn);
    c[ci] = cn;
    h_out[ci] = (bf16_t)hn;
    if (enc_out) enc_out[((long)b_idx * TT + t) * UU + j] = (bf16_t)hn;
  }
}

// ---------------------------------------------------------------------------
// Attention step, online softmax, multi-value butterfly score reduction.
// grid = 256 (one WG per batch row) x 256 thr (4 waves); wave owns 64 t.
// Per 8-t chunk: 8 dots reduced simultaneously in 10 shfl (3 fold stages +
// 3 cluster stages); lane ends with score for t = tb + bitrev3(lane&7).
// ---------------------------------------------------------------------------
__global__ __launch_bounds__(256) void attention(
    const bf16_t* __restrict__ h,        // [B,U]
    const bf16_t* __restrict__ enc_out,  // [B,T,U]
    const float* __restrict__ ptr_w, const float* __restrict__ ptr_b,
    float* __restrict__ out,             // [B,T,T]
    int s,                               // decoder step
    bf16_t* __restrict__ xin)            // [B,U] bf16
{
  const int b = blockIdx.x;
  const int tid = threadIdx.x;
  const int wave = tid >> 6;
  const int lane = tid & 63;
  __shared__ float sc[TT];       // raw scaled scores v[t]
  __shared__ float ctxs[4][UU];  // per-wave context partials
  __shared__ float mL[4], lL[4];

  bf16x8 hv = *(const bf16x8*)(h + b * UU + lane * 8);
  float hf[8];
#pragma unroll
  for (int j = 0; j < 8; ++j) hf[j] = (float)hv[j];

  const bf16_t* eb = enc_out + (long)b * TT * UU;
  const float pw = *ptr_w, pb = *ptr_b;

  float m = -1e30f, l = 0.f;
  float ctx[8];
#pragma unroll
  for (int j = 0; j < 8; ++j) ctx[j] = 0.f;

  for (int ch = 0; ch < 8; ++ch) {
    const int tb = wave * 64 + ch * 8;
    bf16x8 er[8];
#pragma unroll
    for (int q = 0; q < 8; ++q)
      er[q] = *(const bf16x8*)(eb + (long)(tb + q) * UU + lane * 8);
    float v[8];
#pragma unroll
    for (int q = 0; q < 8; ++q) {
      float d = 0.f;
#pragma unroll
      for (int j = 0; j < 8; ++j) d += hf[j] * (float)er[q][j];
      v[q] = d;
    }
    // fold stage m=1 (8->4): send not-kept half, keep half by bit0
    {
      int up = lane & 1;
      float x[4], n4[4];
#pragma unroll
      for (int i = 0; i < 4; ++i) x[i] = up ? v[i] : v[i + 4];
#pragma unroll
      for (int i = 0; i < 4; ++i) {
        float r = __shfl_xor(x[i], 1);
        n4[i] = (up ? v[i + 4] : v[i]) + r;
      }
#pragma unroll
      for (int i = 0; i < 4; ++i) v[i] = n4[i];
    }
    // fold stage m=2 (4->2)
    {
      int up = lane & 2;
      float x0 = up ? v[0] : v[2], x1 = up ? v[1] : v[3];
      float r0 = __shfl_xor(x0, 2), r1 = __shfl_xor(x1, 2);
      float n0 = (up ? v[2] : v[0]) + r0;
      float n1 = (up ? v[3] : v[1]) + r1;
      v[0] = n0;
      v[1] = n1;
    }
    // fold stage m=4 (2->1) + cluster butterfly
    float d;
    {
      int up = lane & 4;
      float x = up ? v[0] : v[1];
      float r = __shfl_xor(x, 4);
      d = (up ? v[1] : v[0]) + r;
    }
    d += __shfl_xor(d, 8);
    d += __shfl_xor(d, 16);
    d += __shfl_xor(d, 32);
    // lane holds full dot for t = tb + q, q = bitrev3(lane&7)
    float score = d * pw + pb;
    if (lane < 8) {
      static const int qperm[8] = {0, 4, 2, 6, 1, 5, 3, 7};
      sc[tb + qperm[lane]] = score;
    }
    // chunk max over the 8 distinct scores (octet-local butterfly)
    float cm = score;
    cm = fmaxf(cm, __shfl_xor(cm, 1));
    cm = fmaxf(cm, __shfl_xor(cm, 2));
    cm = fmaxf(cm, __shfl_xor(cm, 4));
    float mn = fmaxf(m, cm);
    float scale = __expf(m - mn);  // first chunk: 0
    float w = __expf(score - mn);
    // broadcast the 8 w's (value q lives at lane bitrev3(q))
    float wq[8];
    wq[0] = __shfl(w, 0);
    wq[1] = __shfl(w, 4);
    wq[2] = __shfl(w, 2);
    wq[3] = __shfl(w, 6);
    wq[4] = __shfl(w, 1);
    wq[5] = __shfl(w, 5);
    wq[6] = __shfl(w, 3);
    wq[7] = __shfl(w, 7);
    l = l * scale + (((wq[0] + wq[1]) + (wq[2] + wq[3])) +
                     ((wq[4] + wq[5]) + (wq[6] + wq[7])));
#pragma unroll
    for (int j = 0; j < 8; ++j) {
      float cj = ctx[j] * scale;
#pragma unroll
      for (int q = 0; q < 8; ++q) cj += wq[q] * (float)er[q][j];
      ctx[j] = cj;
    }
    m = mn;
  }

  // Publish per-wave state
#pragma unroll
  for (int j = 0; j < 8; ++j) ctxs[wave][lane * 8 + j] = ctx[j];
  if (lane == 0) {
    mL[wave] = m;
    lL[wave] = l;
  }
  __syncthreads();

  const float M = fmaxf(fmaxf(mL[0], mL[1]), fmaxf(mL[2], mL[3]));
  const float s0 = __expf(mL[0] - M), s1 = __expf(mL[1] - M),
              s2 = __expf(mL[2] - M), s3 = __expf(mL[3] - M);
  const float L = lL[0] * s0 + lL[1] * s1 + lL[2] * s2 + lL[3] * s3;
  const float rinvL = 1.f / L;

  out[((long)b * TT + s) * TT + tid] = __expf(sc[tid] - M) * rinvL;

  const int u0 = 2 * tid;
  float a0 = ctxs[0][u0] * s0 + ctxs[1][u0] * s1 + ctxs[2][u0] * s2 +
             ctxs[3][u0] * s3;
  float a1 = ctxs[0][u0 + 1] * s0 + ctxs[1][u0 + 1] * s1 +
             ctxs[2][u0 + 1] * s2 + ctxs[3][u0 + 1] * s3;
  bf16x2 o;
  o[0] = (bf16_t)(a0 * rinvL);
  o[1] = (bf16_t)(a1 * rinvL);
  *(bf16x2*)(xin + b * UU + u0) = o;
}

// ---------------------------------------------------------------------------
extern "C" void kernel_launch(void* const* d_in, const int* in_sizes, int n_in,
                              void* d_out, int out_size, void* d_ws,
                              size_t ws_size, hipStream_t stream) {
  const float* inputs = (const float*)d_in[0];
  const float* score = (const float*)d_in[1];
  const float* enc_Wx = (const float*)d_in[2];
  const float* enc_Wh = (const float*)d_in[3];
  const float* enc_b = (const float*)d_in[4];
  const float* dec_Wx = (const float*)d_in[5];
  const float* dec_Wh = (const float*)d_in[6];
  const float* dec_b = (const float*)d_in[7];
  const float* ptr_w = (const float*)d_in[8];
  const float* ptr_b = (const float*)d_in[9];
  float* out = (float*)d_out;

  char* ws = (char*)d_ws;
  size_t off = 0;
  bf16_t* WencP = (bf16_t*)(ws + off); off += (size_t)2048 * 1024 * 2;
  bf16_t* WdecP = (bf16_t*)(ws + off); off += (size_t)2048 * 1024 * 2;
  bf16_t* enc_out = (bf16_t*)(ws + off); off += (size_t)BB * TT * UU * 2;
  bf16_t* Xbf = (bf16_t*)(ws + off); off += (size_t)TT * BB * UU * 2;
  bf16_t* hb0 = (bf16_t*)(ws + off); off += (size_t)BB * UU * 2;
  bf16_t* hb1 = (bf16_t*)(ws + off); off += (size_t)BB * UU * 2;
  float* cbuf = (float*)(ws + off); off += (size_t)BB * UU * 4;
  bf16_t* xin = (bf16_t*)(ws + off); off += (size_t)BB * UU * 2;
  if (ws_size < off) return;  // insufficient scratch -> loud failure

  prep_weights<<<4096, 64, 0, stream>>>(enc_Wx, enc_Wh, WencP);
  prep_weights<<<4096, 64, 0, stream>>>(dec_Wx, dec_Wh, WdecP);
  prep_x<<<65536, 256, 0, stream>>>(inputs, score, Xbf);
  init_state<<<512, 256, 0, stream>>>(hb0, hb1, cbuf);
  mean_kernel<<<512, 256, 0, stream>>>(Xbf, xin);

  bf16_t* hp[2] = {hb0, hb1};
  int p = 0;
  for (int t = 0; t < TT; ++t) {
    lstm_step<<<512, 256, 0, stream>>>(Xbf + (long)t * BB * UU, WencP, enc_b,
                                       hp[p], hp[1 - p], cbuf, enc_out, t);
    p ^= 1;
  }
  for (int s = 0; s < TT; ++s) {
    lstm_step<<<512, 256, 0, stream>>>(xin, WdecP, dec_b, hp[p], hp[1 - p],
                                       cbuf, nullptr, 0);
    attention<<<256, 256, 0, stream>>>(hp[1 - p], enc_out, ptr_w, ptr_b, out,
                                       s, xin);
    p ^= 1;
  }
}